// Round 13
// baseline (628.995 us; speedup 1.0000x reference)
//
#include <hip/hip_runtime.h>
#include <hip/hip_bf16.h>
#include <stdint.h>

#define T_TOK 4096
#define NEXP  8
#define HDIM  1024
#define IDIM  2048
#define TOPK  2

typedef __attribute__((ext_vector_type(8))) short short8;
typedef __attribute__((ext_vector_type(4))) float f32x4;

__device__ __forceinline__ unsigned short f2bf(float f) {
    union { float f; unsigned int u; } v; v.f = f;
    unsigned int u = v.u;
    return (unsigned short)((u + 0x7fffu + ((u >> 16) & 1u)) >> 16);
}
__device__ __forceinline__ void gload_lds16(const void* g, void* l) {
    __builtin_amdgcn_global_load_lds(
        (const __attribute__((address_space(1))) unsigned int*)g,
        (__attribute__((address_space(3))) unsigned int*)l,
        16, 0, 0);
}
#define MFMA16(A, B, C) __builtin_amdgcn_mfma_f32_16x16x32_bf16(A, B, C, 0, 0, 0)

__device__ __forceinline__ int ld_acq(int* p) {
    return __hip_atomic_load(p, __ATOMIC_ACQUIRE, __HIP_MEMORY_SCOPE_AGENT);
}
__device__ __forceinline__ void add_rel(int* p, int v) {
    __hip_atomic_fetch_add(p, v, __ATOMIC_RELEASE, __HIP_MEMORY_SCOPE_AGENT);
}
__device__ __forceinline__ void cvt8(const float* s, unsigned short* d, size_t u) {
    const float4* p4 = (const float4*)(s + u * 8);
    float4 a = p4[0], b = p4[1];
    union { unsigned short us[8]; short8 v; } r;
    r.us[0] = f2bf(a.x); r.us[1] = f2bf(a.y); r.us[2] = f2bf(a.z); r.us[3] = f2bf(a.w);
    r.us[4] = f2bf(b.x); r.us[5] = f2bf(b.y); r.us[6] = f2bf(b.z); r.us[7] = f2bf(b.w);
    *(short8*)(d + u * 8) = r.v;
}
__device__ __forceinline__ void top2(const float* lp8, int& e0, int& e1, float& w0) {
    const float4* lp = (const float4*)lp8;
    float4 a = lp[0], b = lp[1];
    float l[NEXP] = {a.x, a.y, a.z, a.w, b.x, b.y, b.z, b.w};
    e0 = 0; float b0 = l[0];
    #pragma unroll
    for (int e = 1; e < NEXP; ++e) if (l[e] > b0) { b0 = l[e]; e0 = e; }
    e1 = -1; float b1 = -1e30f;
    #pragma unroll
    for (int e = 0; e < NEXP; ++e) { if (e == e0) continue; if (l[e] > b1) { b1 = l[e]; e1 = e; } }
    w0 = 1.0f / (1.0f + __expf(b1 - b0));
}

// ---------------- fused1: route + cvt(x,w13,w2) + gemm1, one kernel, work queue ----------------
// queue: [0]=route  [1,65)=xb  [65,1089)=w13 panel-pieces  [1089,1217)=w2  [1217,2369)=gemm1
// sync[]: 0=qhead 1=route_done 2=xb_cnt 8+p=pan_cnt[p] (p = e*16+nt, 128 panels)

#define IT_XB   1
#define IT_W13  65
#define IT_W2   1089
#define IT_G1   1217
#define NBLK    2369
#define PWIN    32

__global__ __launch_bounds__(256, 2) void fused1_k(
    const float* __restrict__ logits, const float* __restrict__ x,
    const float* __restrict__ w13, const float* __restrict__ w2,
    int* __restrict__ sync, int* __restrict__ offs, int* __restrict__ work,
    int* __restrict__ tokid, float* __restrict__ tokw,
    unsigned short* __restrict__ xb, unsigned short* __restrict__ w13b,
    unsigned short* __restrict__ w2b, unsigned short* __restrict__ hbuf)
{
    __shared__ __align__(16) unsigned short As[128 * 64];
    __shared__ __align__(16) unsigned short Bg[128 * 64];
    __shared__ __align__(16) unsigned short Bu[128 * 64];
    __shared__ int s_item;
    __shared__ int s_cnt[NEXP], s_cur[NEXP];

    const int tid = threadIdx.x;
    if (tid == 0) s_item = atomicAdd(&sync[0], 1);
    __syncthreads();
    const int item = s_item;

    if (item == 0) {
        // ---- routing (two-pass, 256 threads)
        if (tid < NEXP) s_cnt[tid] = 0;
        __syncthreads();
        for (int t = tid; t < T_TOK; t += 256) {
            int e0, e1; float w0;
            top2(logits + (size_t)t * NEXP, e0, e1, w0);
            atomicAdd(&s_cnt[e0], 1); atomicAdd(&s_cnt[e1], 1);
        }
        __syncthreads();
        if (tid == 0) {
            int s = 0, n = 0;
            for (int e = 0; e < NEXP; ++e) {
                offs[e] = s; s_cur[e] = s;
                int nm = (s_cnt[e] + 127) >> 7;
                for (int m = 0; m < nm; ++m) work[1 + n++] = (e << 8) | m;
                s += s_cnt[e];
            }
            offs[NEXP] = s;
            work[0] = n;
        }
        __syncthreads();
        for (int t = tid; t < T_TOK; t += 256) {
            int e0, e1; float w0;
            top2(logits + (size_t)t * NEXP, e0, e1, w0);
            int p0 = atomicAdd(&s_cur[e0], 1);
            tokid[p0] = t; tokw[p0] = w0;
            int p1 = atomicAdd(&s_cur[e1], 1);
            tokid[p1] = t; tokw[p1] = 1.0f - w0;
        }
        __threadfence();
        __syncthreads();
        if (tid == 0) add_rel(&sync[1], 1);
        return;
    }
    if (item < IT_W13) {
        // ---- xb convert: 64 items x 8192 float8-units
        const int j = item - IT_XB;
        const size_t base = (size_t)j * 8192;
        for (int u = tid; u < 8192; u += 256) cvt8(x, xb, base + u);
        __threadfence();
        __syncthreads();
        if (tid == 0) add_rel(&sync[2], 1);
        return;
    }
    if (item < IT_W2) {
        // ---- w13 panel piece: panel p (= e*16+nt, 256 rows: 128 gate + 128 up), piece pc of 8
        const int pi = item - IT_W13;
        const int p = pi >> 3, pc = pi & 7;
        if (p >= PWIN) {
            if (tid == 0) { while (ld_acq(&sync[8 + p - PWIN]) < 8) __builtin_amdgcn_s_sleep(8); }
            __syncthreads();
        }
        const int e = p >> 4, nt = p & 15;
        for (int u = tid; u < 4096; u += 256) {        // 32 rows x 128 units
            int r = pc * 32 + (u >> 7), c8 = u & 127;
            int srcrow = (r < 128) ? nt * 128 + r : IDIM + nt * 128 + (r - 128);
            size_t o = ((size_t)e * 2 * IDIM + srcrow) * HDIM / 8 + c8;
            cvt8(w13, w13b, o);
        }
        __threadfence();
        __syncthreads();
        if (tid == 0) add_rel(&sync[8 + p], 1);
        return;
    }
    if (item < IT_G1) {
        // ---- w2 convert: 128 items x 16384 units (consumed by next kernel)
        const int j = item - IT_W2;
        const size_t base = (size_t)j * 16384;
        for (int u = tid; u < 16384; u += 256) cvt8(w2, w2b, base + u);
        return;
    }

    // ---- gemm1 (frozen R11 16x16 structure) with dependency gates
    if (tid == 0) { while (ld_acq(&sync[1]) < 1) __builtin_amdgcn_s_sleep(8); }
    __syncthreads();

    const int id = item - IT_G1;                 // 0..1151
    const int id2 = (id & 7) * 144 + (id >> 3);  // XCD-chunked bijective swizzle
    const int nt = id2 / 72;
    const int wki = id2 % 72;
    if (wki >= work[0]) return;
    const int wk = work[1 + wki];
    const int e = wk >> 8, mt = wk & 255;
    const int off_e = offs[e];
    const int cnt_e = offs[e + 1] - off_e;

    if (tid == 0) {
        while (ld_acq(&sync[2]) < 64) __builtin_amdgcn_s_sleep(8);                 // xb ready
        while (ld_acq(&sync[8 + (e * 16 + nt)]) < 8) __builtin_amdgcn_s_sleep(8);  // panel ready
    }
    __syncthreads();

    const int w = tid >> 6, lane = tid & 63;
    const int ln15 = lane & 15, l16 = lane >> 4;
    const int wm = w >> 1, wn = w & 1;

    const unsigned short* aSrc[4]; const unsigned short* gSrc[4]; const unsigned short* uSrc[4];
    int ldsOff[4];
    #pragma unroll
    for (int i = 0; i < 4; ++i) {
        int S = (i * 4 + w) * 64 + lane;
        int row = S >> 3;
        int ko = (S & 7) ^ (row & 7);
        ldsOff[i] = (i * 4 + w) * 512;
        int tr = mt * 128 + row; if (tr >= cnt_e) tr = cnt_e - 1;
        aSrc[i] = xb + (size_t)tokid[off_e + tr] * HDIM + ko * 8;
        gSrc[i] = w13b + (size_t)e * (2 * IDIM * HDIM) + (size_t)(nt * 128 + row) * HDIM + ko * 8;
        uSrc[i] = w13b + (size_t)e * (2 * IDIM * HDIM) + (size_t)(IDIM + nt * 128 + row) * HDIM + ko * 8;
    }

    const f32x4 z4 = {0.f, 0.f, 0.f, 0.f};
    f32x4 g[4][4], u[4][4];
    #pragma unroll
    for (int m = 0; m < 4; ++m)
        #pragma unroll
        for (int n = 0; n < 4; ++n) { g[m][n] = z4; u[m][n] = z4; }

    const int KT = HDIM / 64;   // 16
    for (int kt = 0; kt < KT; ++kt) {
        #pragma unroll
        for (int i = 0; i < 4; ++i) {
            gload_lds16(aSrc[i] + kt * 64, &As[ldsOff[i]]);
            gload_lds16(gSrc[i] + kt * 64, &Bg[ldsOff[i]]);
            gload_lds16(uSrc[i] + kt * 64, &Bu[ldsOff[i]]);
        }
        __syncthreads();
        #pragma unroll
        for (int kk = 0; kk < 2; ++kk) {
            short8 av[4], bgv[4], buv[4];
            int ko = kk * 4 + l16;
            #pragma unroll
            for (int m = 0; m < 4; ++m) {
                int row = wm * 64 + m * 16 + ln15;
                av[m] = *(const short8*)(As + row * 64 + ((ko ^ (row & 7)) * 8));
            }
            #pragma unroll
            for (int n = 0; n < 4; ++n) {
                int row = wn * 64 + n * 16 + ln15;
                int idx = row * 64 + ((ko ^ (row & 7)) * 8);
                bgv[n] = *(const short8*)(Bg + idx);
                buv[n] = *(const short8*)(Bu + idx);
            }
            __builtin_amdgcn_s_setprio(1);
            #pragma unroll
            for (int m = 0; m < 4; ++m)
                #pragma unroll
                for (int n = 0; n < 4; ++n) {
                    g[m][n] = MFMA16(av[m], bgv[n], g[m][n]);
                    u[m][n] = MFMA16(av[m], buv[n], u[m][n]);
                }
            __builtin_amdgcn_s_setprio(0);
        }
        __syncthreads();
    }

    #pragma unroll
    for (int m = 0; m < 4; ++m) {
        #pragma unroll
        for (int i = 0; i < 4; ++i) {
            int r = mt * 128 + wm * 64 + m * 16 + l16 * 4 + i;
            if (r >= cnt_e) continue;
            size_t rb = (size_t)(off_e + r) * IDIM;
            #pragma unroll
            for (int n = 0; n < 4; ++n) {
                int col = nt * 128 + wn * 64 + n * 16 + ln15;
                float gv = g[m][n][i], uv = u[m][n][i];
                float hv = gv / (1.f + __expf(-gv)) * uv;
                hbuf[rb + col] = f2bf(hv);
            }
        }
    }
}

// ---------------- gemm2c: (h @ W2^T) * tokw + fused combine (R11 exact) ----------------

__global__ __launch_bounds__(256, 2) void gemm2c_k(
    const unsigned short* __restrict__ hbuf, const unsigned short* __restrict__ w2b,
    const int* __restrict__ tokid, const int* __restrict__ offs,
    const int* __restrict__ work, const float* __restrict__ tokw,
    float* __restrict__ out)
{
    __shared__ __align__(16) unsigned short As[128 * 64];
    __shared__ __align__(16) unsigned short Bs[128 * 64];

    const int id = blockIdx.y * gridDim.x + blockIdx.x;   // 0..575
    const int id2 = (id & 7) * 72 + (id >> 3);
    const int nt = id2 / 72;
    const int wki = id2 % 72;
    if (wki >= work[0]) return;
    const int wk = work[1 + wki];
    const int e = wk >> 8, mt = wk & 255;
    const int off_e = offs[e];
    const int cnt_e = offs[e + 1] - off_e;

    const int tid = threadIdx.x;
    const int w = tid >> 6, lane = tid & 63;
    const int ln15 = lane & 15, l16 = lane >> 4;
    const int wm = w >> 1, wn = w & 1;

    const unsigned short* aSrc[4]; const unsigned short* bSrc[4];
    int ldsOff[4];
    #pragma unroll
    for (int i = 0; i < 4; ++i) {
        int S = (i * 4 + w) * 64 + lane;
        int row = S >> 3;
        int ko = (S & 7) ^ (row & 7);
        ldsOff[i] = (i * 4 + w) * 512;
        int tr = mt * 128 + row; if (tr >= cnt_e) tr = cnt_e - 1;
        aSrc[i] = hbuf + (size_t)(off_e + tr) * IDIM + ko * 8;
        bSrc[i] = w2b + (size_t)e * (HDIM * IDIM) + (size_t)(nt * 128 + row) * IDIM + ko * 8;
    }

    const f32x4 z4 = {0.f, 0.f, 0.f, 0.f};
    f32x4 acc[4][4];
    #pragma unroll
    for (int m = 0; m < 4; ++m)
        #pragma unroll
        for (int n = 0; n < 4; ++n) acc[m][n] = z4;

    const int KT = IDIM / 64;   // 32
    for (int kt = 0; kt < KT; ++kt) {
        #pragma unroll
        for (int i = 0; i < 4; ++i) {
            gload_lds16(aSrc[i] + kt * 64, &As[ldsOff[i]]);
            gload_lds16(bSrc[i] + kt * 64, &Bs[ldsOff[i]]);
        }
        __syncthreads();
        #pragma unroll
        for (int kk = 0; kk < 2; ++kk) {
            short8 av[4], bv[4];
            int ko = kk * 4 + l16;
            #pragma unroll
            for (int m = 0; m < 4; ++m) {
                int row = wm * 64 + m * 16 + ln15;
                av[m] = *(const short8*)(As + row * 64 + ((ko ^ (row & 7)) * 8));
            }
            #pragma unroll
            for (int n = 0; n < 4; ++n) {
                int row = wn * 64 + n * 16 + ln15;
                bv[n] = *(const short8*)(Bs + row * 64 + ((ko ^ (row & 7)) * 8));
            }
            __builtin_amdgcn_s_setprio(1);
            #pragma unroll
            for (int m = 0; m < 4; ++m)
                #pragma unroll
                for (int n = 0; n < 4; ++n)
                    acc[m][n] = MFMA16(av[m], bv[n], acc[m][n]);
            __builtin_amdgcn_s_setprio(0);
        }
        __syncthreads();
    }

    #pragma unroll
    for (int m = 0; m < 4; ++m) {
        #pragma unroll
        for (int i = 0; i < 4; ++i) {
            int r = mt * 128 + wm * 64 + m * 16 + l16 * 4 + i;
            if (r >= cnt_e) continue;
            int tok = tokid[off_e + r];
            float wgt = tokw[off_e + r];
            float* orow = out + (size_t)tok * HDIM;
            #pragma unroll
            for (int n = 0; n < 4; ++n) {
                int col = nt * 128 + wn * 64 + n * 16 + ln15;
                atomicAdd(&orow[col], wgt * acc[m][n][i]);
            }
        }
    }
}

// ---------------- launch ----------------

extern "C" void kernel_launch(void* const* d_in, const int* in_sizes, int n_in,
                              void* d_out, int out_size, void* d_ws, size_t ws_size,
                              hipStream_t stream) {
    const float* x      = (const float*)d_in[0];
    const float* logits = (const float*)d_in[1];
    const float* w13    = (const float*)d_in[2];
    const float* w2     = (const float*)d_in[3];
    float* out = (float*)d_out;

    char* ws = (char*)d_ws;
    size_t off = 0;
    auto carve = [&](size_t bytes) -> void* {
        void* p = ws + off;
        off = (off + bytes + 255) & ~(size_t)255;
        return p;
    };
    int*   sync   = (int*)carve(1024);
    int*   offs   = (int*)carve((NEXP + 1) * 4);
    int*   work   = (int*)carve(128 * 4);
    int*   tokid  = (int*)carve((size_t)(T_TOK * TOPK + 256) * 4);
    float* tokw   = (float*)carve((size_t)T_TOK * TOPK * 4);
    unsigned short* xb   = (unsigned short*)carve((size_t)T_TOK * HDIM * 2);
    unsigned short* w13b = (unsigned short*)carve((size_t)NEXP * 2 * IDIM * HDIM * 2);
    unsigned short* w2b  = (unsigned short*)carve((size_t)NEXP * HDIM * IDIM * 2);
    unsigned short* hbuf = (unsigned short*)carve((size_t)T_TOK * TOPK * IDIM * 2);

    hipMemsetAsync(sync, 0, 1024, stream);
    hipMemsetAsync(out, 0, (size_t)T_TOK * HDIM * sizeof(float), stream);
    fused1_k<<<NBLK, 256, 0, stream>>>(logits, x, w13, w2, sync, offs, work,
                                       tokid, tokw, xb, w13b, w2b, hbuf);
    gemm2c_k<<<dim3(8, 72, 1), 256, 0, stream>>>(hbuf, w2b, tokid, offs, work, tokw, out);
}